// Round 8
// baseline (91.719 us; speedup 1.0000x reference)
//
#include <hip/hip_runtime.h>
#include <math.h>

#define NQ   4
#define NL   2
#define CD   128      // C
#define HWSZ 16384    // H*W
#define OUTC 128      // OUT

typedef float f4 __attribute__((ext_vector_type(4)));

// ---------------------------------------------------------------------------
// Setup kernel: build A[4][81] Pauli-string coefficients from circuit weights.
//   z_w(pixel) = sum_j A[w][j] * prod_i t_{i, j_i},  t_i = (1, cos(pi*xq_i), sin(pi*xq_i))
// ---------------------------------------------------------------------------
__global__ void qsetup_kernel(const float* __restrict__ qw, float* __restrict__ A) {
    __shared__ float Ur[16][17];  // Ur[col][k] = Re U[k][col]
    __shared__ float Ui[16][17];
    __shared__ float sM[4 * 16 * 16];
    const int tid = threadIdx.x;

    if (tid < 16) {
        float sr[16], si[16];
        #pragma unroll
        for (int k = 0; k < 16; ++k) { sr[k] = (k == tid) ? 1.f : 0.f; si[k] = 0.f; }

        #pragma unroll
        for (int l = 0; l < NL; ++l) {
            #pragma unroll
            for (int w = 0; w < NQ; ++w) {
                float phi = qw[(l * NQ + w) * 3 + 0];
                float th  = qw[(l * NQ + w) * 3 + 1];
                float om  = qw[(l * NQ + w) * 3 + 2];
                float ct = cosf(0.5f * th), st = sinf(0.5f * th);
                float a = 0.5f * (phi + om), b = 0.5f * (phi - om);
                float sa, ca, sb, cb;
                sincosf(a, &sa, &ca);
                sincosf(b, &sb, &cb);
                float u00r =  ca * ct, u00i = -sa * ct;
                float u01r = -cb * st, u01i = -sb * st;
                float u10r =  cb * st, u10i = -sb * st;
                float u11r =  ca * ct, u11i =  sa * ct;
                const int wm = 1 << (3 - w);
                #pragma unroll
                for (int i = 0; i < 16; ++i) {
                    if (i & wm) continue;
                    int i1 = i | wm;
                    float a0r = sr[i],  a0i = si[i];
                    float a1r = sr[i1], a1i = si[i1];
                    sr[i]  = u00r * a0r - u00i * a0i + u01r * a1r - u01i * a1i;
                    si[i]  = u00r * a0i + u00i * a0r + u01r * a1i + u01i * a1r;
                    sr[i1] = u10r * a0r - u10i * a0i + u11r * a1r - u11i * a1i;
                    si[i1] = u10r * a0i + u10i * a0r + u11r * a1i + u11i * a1r;
                }
            }
            const int r = l % (NQ - 1) + 1;
            #pragma unroll
            for (int w = 0; w < NQ; ++w) {
                const int cm = 1 << (3 - w);
                const int tm = 1 << (3 - ((w + r) % NQ));
                #pragma unroll
                for (int i = 0; i < 16; ++i) {
                    if ((i & cm) && !(i & tm)) {
                        int i1 = i | tm;
                        float t;
                        t = sr[i]; sr[i] = sr[i1]; sr[i1] = t;
                        t = si[i]; si[i] = si[i1]; si[i1] = t;
                    }
                }
            }
        }
        #pragma unroll
        for (int k = 0; k < 16; ++k) { Ur[tid][k] = sr[k]; Ui[tid][k] = si[k]; }
    }
    __syncthreads();

    for (int t = tid; t < 4 * 16 * 16; t += blockDim.x) {
        int w = t >> 8, rem = t & 255, i = rem >> 4, j = rem & 15;
        float acc = 0.f;
        #pragma unroll
        for (int k = 0; k < 16; ++k) {
            float sgn = ((k >> (3 - w)) & 1) ? -1.f : 1.f;
            acc += sgn * (Ur[i][k] * Ur[j][k] + Ui[i][k] * Ui[j][k]);
        }
        sM[t] = acc;
    }
    __syncthreads();

    for (int t = tid; t < 4 * 81; t += blockDim.x) {
        int w = t / 81, j = t % 81;
        int j0 = j / 27, j1 = (j / 9) % 3, j2 = (j / 3) % 3, j3 = j % 3;
        int f =  ((j0 == 2) ? 8 : 0) | ((j1 == 2) ? 4 : 0)
               | ((j2 == 2) ? 2 : 0) | ((j3 == 2) ? 1 : 0);
        int zm = ((j0 == 1) ? 8 : 0) | ((j1 == 1) ? 4 : 0)
               | ((j2 == 1) ? 2 : 0) | ((j3 == 1) ? 1 : 0);
        float acc = 0.f;
        #pragma unroll
        for (int i = 0; i < 16; ++i) {
            float sgn = (__popc(i & zm) & 1) ? -1.f : 1.f;
            acc += sM[(w * 16 + (i ^ f)) * 16 + i] * sgn;
        }
        A[t] = acc * 0.0625f;
    }
}

// ---------------------------------------------------------------------------
// Shared device helper: angles -> z[4] via Pauli coefficients
// ---------------------------------------------------------------------------
__device__ __forceinline__ void circuit_z(float a0, float a1, float a2, float a3,
                                          const float* __restrict__ A,
                                          float& z0, float& z1, float& z2, float& z3)
{
    const float PI = 3.14159265358979323846f;
    float cz0, sx0, cz1, sx1, cz2, sx2, cz3, sx3;
    sincosf(PI * a0, &sx0, &cz0);
    sincosf(PI * a1, &sx1, &cz1);
    sincosf(PI * a2, &sx2, &cz2);
    sincosf(PI * a3, &sx3, &cz3);

    float g01[9], g23[9];
    float t0[3] = { 1.f, cz0, sx0 }, t1[3] = { 1.f, cz1, sx1 };
    float t2[3] = { 1.f, cz2, sx2 }, t3[3] = { 1.f, cz3, sx3 };
    #pragma unroll
    for (int a = 0; a < 3; ++a)
        #pragma unroll
        for (int b = 0; b < 3; ++b) {
            g01[a * 3 + b] = t0[a] * t1[b];
            g23[a * 3 + b] = t2[a] * t3[b];
        }

    z0 = z1 = z2 = z3 = 0.f;
    #pragma unroll
    for (int j01 = 0; j01 < 9; ++j01)
        #pragma unroll
        for (int j23 = 0; j23 < 9; ++j23) {
            float g = g01[j01] * g23[j23];
            int j = j01 * 9 + j23;
            z0 = fmaf(A[  0 + j], g, z0);
            z1 = fmaf(A[ 81 + j], g, z1);
            z2 = fmaf(A[162 + j], g, z2);
            z3 = fmaf(A[243 + j], g, z3);
        }
}

// ---------------------------------------------------------------------------
// Main fused kernel: thread owns a QUAD of 4 consecutive pixels.
// All x reads are float4 (1KB per wave-instruction), all out writes are
// NT float4. Loads batched 16-deep -> 16KB in flight per wave.
// 64-thread blocks, grid = 512 (2 blocks/CU).
// ---------------------------------------------------------------------------
__global__ __launch_bounds__(64) void qquad_kernel(
    const float* __restrict__ x, const float* __restrict__ pre_w,
    const float* __restrict__ pre_b, const float* __restrict__ A,
    const float* __restrict__ post_w, const float* __restrict__ post_b,
    float* __restrict__ out)
{
    const int lane = threadIdx.x;
    const int pq   = blockIdx.x * 64 + lane;   // pixel-quad id, total 32768
    const int n    = pq >> 12;                 // 4096 quads per image
    const int hw0  = (pq & 4095) * 4;
    const float* xp = x + (size_t)n * CD * HWSZ + hw0;

    // acc[px][q]
    float acc[4][4];
    #pragma unroll
    for (int px = 0; px < 4; ++px)
        #pragma unroll
        for (int q = 0; q < 4; ++q)
            acc[px][q] = pre_b[q];

    #pragma unroll
    for (int c0 = 0; c0 < CD; c0 += 16) {
        f4 xv[16];
        #pragma unroll
        for (int j = 0; j < 16; ++j)
            xv[j] = *reinterpret_cast<const f4*>(&xp[(size_t)(c0 + j) * HWSZ]);
        #pragma unroll
        for (int j = 0; j < 16; ++j) {
            const int c = c0 + j;
            const float w0 = pre_w[0 * CD + c], w1 = pre_w[1 * CD + c];
            const float w2 = pre_w[2 * CD + c], w3 = pre_w[3 * CD + c];
            #pragma unroll
            for (int px = 0; px < 4; ++px) {
                const float xs = xv[j][px];
                acc[px][0] = fmaf(xs, w0, acc[px][0]);
                acc[px][1] = fmaf(xs, w1, acc[px][1]);
                acc[px][2] = fmaf(xs, w2, acc[px][2]);
                acc[px][3] = fmaf(xs, w3, acc[px][3]);
            }
        }
    }

    // circuit per pixel (cheap: ~250 VALU each)
    float z[4][4];
    #pragma unroll
    for (int px = 0; px < 4; ++px)
        circuit_z(acc[px][0], acc[px][1], acc[px][2], acc[px][3], A,
                  z[px][0], z[px][1], z[px][2], z[px][3]);

    float* op = out + (size_t)n * OUTC * HWSZ + hw0;
    #pragma unroll 8
    for (int o = 0; o < OUTC; ++o) {
        const f4 wv = *reinterpret_cast<const f4*>(&post_w[o * NQ]);
        const float bias = post_b[o];
        f4 v;
        #pragma unroll
        for (int px = 0; px < 4; ++px)
            v[px] = fmaf(z[px][0], wv.x, fmaf(z[px][1], wv.y,
                    fmaf(z[px][2], wv.z, fmaf(z[px][3], wv.w, bias))));
        __builtin_nontemporal_store(v, reinterpret_cast<f4*>(&op[(size_t)o * HWSZ]));
    }
}

extern "C" void kernel_launch(void* const* d_in, const int* in_sizes, int n_in,
                              void* d_out, int out_size, void* d_ws, size_t ws_size,
                              hipStream_t stream) {
    const float* x      = (const float*)d_in[0];
    const float* pre_w  = (const float*)d_in[1];
    const float* pre_b  = (const float*)d_in[2];
    const float* qw     = (const float*)d_in[3];
    const float* post_w = (const float*)d_in[4];
    const float* post_b = (const float*)d_in[5];
    float* out = (float*)d_out;
    float* A   = (float*)d_ws;   // 4*81 floats

    hipLaunchKernelGGL(qsetup_kernel, dim3(1), dim3(256), 0, stream, qw, A);

    const int B = in_sizes[0] / CD;   // N*H*W pixels = 131072
    hipLaunchKernelGGL(qquad_kernel, dim3(B / 4 / 64), dim3(64), 0, stream,
                       x, pre_w, pre_b, A, post_w, post_b, out);
}

// Round 9
// 46.967 us; speedup vs baseline: 1.9529x; 1.9529x over previous
//
#include <hip/hip_runtime.h>
#include <math.h>

#define NQ   4
#define NL   2
#define CD   128      // C
#define HWSZ 16384    // H*W
#define OUTC 128      // OUT

// ---------------------------------------------------------------------------
// Setup kernel: build A[4][81] Pauli-string coefficients from circuit weights.
//   z_w(pixel) = sum_j A[w][j] * prod_i t_{i, j_i},  t_i = (1, cos(pi*xq_i), sin(pi*xq_i))
// ---------------------------------------------------------------------------
__global__ void qsetup_kernel(const float* __restrict__ qw, float* __restrict__ A) {
    __shared__ float Ur[16][17];  // Ur[col][k] = Re U[k][col]
    __shared__ float Ui[16][17];
    __shared__ float sM[4 * 16 * 16];
    const int tid = threadIdx.x;

    if (tid < 16) {
        float sr[16], si[16];
        #pragma unroll
        for (int k = 0; k < 16; ++k) { sr[k] = (k == tid) ? 1.f : 0.f; si[k] = 0.f; }

        #pragma unroll
        for (int l = 0; l < NL; ++l) {
            #pragma unroll
            for (int w = 0; w < NQ; ++w) {
                float phi = qw[(l * NQ + w) * 3 + 0];
                float th  = qw[(l * NQ + w) * 3 + 1];
                float om  = qw[(l * NQ + w) * 3 + 2];
                float ct = cosf(0.5f * th), st = sinf(0.5f * th);
                float a = 0.5f * (phi + om), b = 0.5f * (phi - om);
                float sa, ca, sb, cb;
                sincosf(a, &sa, &ca);
                sincosf(b, &sb, &cb);
                float u00r =  ca * ct, u00i = -sa * ct;
                float u01r = -cb * st, u01i = -sb * st;
                float u10r =  cb * st, u10i = -sb * st;
                float u11r =  ca * ct, u11i =  sa * ct;
                const int wm = 1 << (3 - w);
                #pragma unroll
                for (int i = 0; i < 16; ++i) {
                    if (i & wm) continue;
                    int i1 = i | wm;
                    float a0r = sr[i],  a0i = si[i];
                    float a1r = sr[i1], a1i = si[i1];
                    sr[i]  = u00r * a0r - u00i * a0i + u01r * a1r - u01i * a1i;
                    si[i]  = u00r * a0i + u00i * a0r + u01r * a1i + u01i * a1r;
                    sr[i1] = u10r * a0r - u10i * a0i + u11r * a1r - u11i * a1i;
                    si[i1] = u10r * a0i + u10i * a0r + u11r * a1i + u11i * a1r;
                }
            }
            const int r = l % (NQ - 1) + 1;
            #pragma unroll
            for (int w = 0; w < NQ; ++w) {
                const int cm = 1 << (3 - w);
                const int tm = 1 << (3 - ((w + r) % NQ));
                #pragma unroll
                for (int i = 0; i < 16; ++i) {
                    if ((i & cm) && !(i & tm)) {
                        int i1 = i | tm;
                        float t;
                        t = sr[i]; sr[i] = sr[i1]; sr[i1] = t;
                        t = si[i]; si[i] = si[i1]; si[i1] = t;
                    }
                }
            }
        }
        #pragma unroll
        for (int k = 0; k < 16; ++k) { Ur[tid][k] = sr[k]; Ui[tid][k] = si[k]; }
    }
    __syncthreads();

    for (int t = tid; t < 4 * 16 * 16; t += blockDim.x) {
        int w = t >> 8, rem = t & 255, i = rem >> 4, j = rem & 15;
        float acc = 0.f;
        #pragma unroll
        for (int k = 0; k < 16; ++k) {
            float sgn = ((k >> (3 - w)) & 1) ? -1.f : 1.f;
            acc += sgn * (Ur[i][k] * Ur[j][k] + Ui[i][k] * Ui[j][k]);
        }
        sM[t] = acc;
    }
    __syncthreads();

    for (int t = tid; t < 4 * 81; t += blockDim.x) {
        int w = t / 81, j = t % 81;
        int j0 = j / 27, j1 = (j / 9) % 3, j2 = (j / 3) % 3, j3 = j % 3;
        int f =  ((j0 == 2) ? 8 : 0) | ((j1 == 2) ? 4 : 0)
               | ((j2 == 2) ? 2 : 0) | ((j3 == 2) ? 1 : 0);
        int zm = ((j0 == 1) ? 8 : 0) | ((j1 == 1) ? 4 : 0)
               | ((j2 == 1) ? 2 : 0) | ((j3 == 1) ? 1 : 0);
        float acc = 0.f;
        #pragma unroll
        for (int i = 0; i < 16; ++i) {
            float sgn = (__popc(i & zm) & 1) ? -1.f : 1.f;
            acc += sM[(w * 16 + (i ^ f)) * 16 + i] * sgn;
        }
        A[t] = acc * 0.0625f;
    }
}

// ---------------------------------------------------------------------------
// Main fused kernel (R4 skeleton): one thread per pixel, 32-deep batched
// PLAIN loads (L2/L3 retain x across replays), hardware __sinf/__cosf,
// PLAIN stores (out stays L2/L3-resident in the replay regime; lazy
// writeback instead of forced HBM traffic).
// ---------------------------------------------------------------------------
__global__ __launch_bounds__(256) void qmain_kernel(
    const float* __restrict__ x, const float* __restrict__ pre_w,
    const float* __restrict__ pre_b, const float* __restrict__ A,
    const float* __restrict__ post_w, const float* __restrict__ post_b,
    float* __restrict__ out)
{
    const int tid = threadIdx.x;
    const int p  = blockIdx.x * 256 + tid;   // pixel id
    const int n  = p >> 14;                  // / HWSZ
    const int hw = p & (HWSZ - 1);
    const float* xp = x + (size_t)n * CD * HWSZ + hw;

    float a0 = pre_b[0], a1 = pre_b[1], a2 = pre_b[2], a3 = pre_b[3];
    #pragma unroll
    for (int c0 = 0; c0 < CD; c0 += 32) {
        float xv[32];
        #pragma unroll
        for (int j = 0; j < 32; ++j)
            xv[j] = xp[(size_t)(c0 + j) * HWSZ];
        #pragma unroll
        for (int j = 0; j < 32; ++j) {
            const int c = c0 + j;
            a0 = fmaf(xv[j], pre_w[0 * CD + c], a0);
            a1 = fmaf(xv[j], pre_w[1 * CD + c], a1);
            a2 = fmaf(xv[j], pre_w[2 * CD + c], a2);
            a3 = fmaf(xv[j], pre_w[3 * CD + c], a3);
        }
    }

    // hardware sin/cos (v_sin_f32/v_cos_f32 path); error budget has 6x headroom
    const float PI = 3.14159265358979323846f;
    float cz0 = __cosf(PI * a0), sx0 = __sinf(PI * a0);
    float cz1 = __cosf(PI * a1), sx1 = __sinf(PI * a1);
    float cz2 = __cosf(PI * a2), sx2 = __sinf(PI * a2);
    float cz3 = __cosf(PI * a3), sx3 = __sinf(PI * a3);

    float g01[9], g23[9];
    {
        float t0[3] = { 1.f, cz0, sx0 }, t1[3] = { 1.f, cz1, sx1 };
        float t2[3] = { 1.f, cz2, sx2 }, t3[3] = { 1.f, cz3, sx3 };
        #pragma unroll
        for (int a = 0; a < 3; ++a)
            #pragma unroll
            for (int b = 0; b < 3; ++b) {
                g01[a * 3 + b] = t0[a] * t1[b];
                g23[a * 3 + b] = t2[a] * t3[b];
            }
    }

    float z0 = 0.f, z1 = 0.f, z2 = 0.f, z3 = 0.f;
    #pragma unroll
    for (int j01 = 0; j01 < 9; ++j01)
        #pragma unroll
        for (int j23 = 0; j23 < 9; ++j23) {
            float g = g01[j01] * g23[j23];
            int j = j01 * 9 + j23;
            z0 = fmaf(A[  0 + j], g, z0);
            z1 = fmaf(A[ 81 + j], g, z1);
            z2 = fmaf(A[162 + j], g, z2);
            z3 = fmaf(A[243 + j], g, z3);
        }

    float* op = out + (size_t)n * OUTC * HWSZ + hw;
    #pragma unroll 8
    for (int o = 0; o < OUTC; ++o) {
        float val = fmaf(z0, post_w[o * NQ + 0],
                    fmaf(z1, post_w[o * NQ + 1],
                    fmaf(z2, post_w[o * NQ + 2],
                    fmaf(z3, post_w[o * NQ + 3], post_b[o]))));
        op[(size_t)o * HWSZ] = val;
    }
}

extern "C" void kernel_launch(void* const* d_in, const int* in_sizes, int n_in,
                              void* d_out, int out_size, void* d_ws, size_t ws_size,
                              hipStream_t stream) {
    const float* x      = (const float*)d_in[0];
    const float* pre_w  = (const float*)d_in[1];
    const float* pre_b  = (const float*)d_in[2];
    const float* qw     = (const float*)d_in[3];
    const float* post_w = (const float*)d_in[4];
    const float* post_b = (const float*)d_in[5];
    float* out = (float*)d_out;
    float* A   = (float*)d_ws;   // 4*81 floats

    hipLaunchKernelGGL(qsetup_kernel, dim3(1), dim3(256), 0, stream, qw, A);

    const int B = in_sizes[0] / CD;   // N*H*W pixels
    hipLaunchKernelGGL(qmain_kernel, dim3(B / 256), dim3(256), 0, stream,
                       x, pre_w, pre_b, A, post_w, post_b, out);
}

// Round 10
// 45.244 us; speedup vs baseline: 2.0272x; 1.0381x over previous
//
#include <hip/hip_runtime.h>
#include <math.h>

#define NQ   4
#define NL   2
#define CD   128      // C
#define HWSZ 16384    // H*W
#define OUTC 128      // OUT

// ---------------------------------------------------------------------------
// Setup kernel: build A[4][81] Pauli-string coefficients from circuit weights.
//   z_w(pixel) = sum_j A[w][j] * prod_i t_{i, j_i},  t_i = (1, cos(pi*xq_i), sin(pi*xq_i))
// ---------------------------------------------------------------------------
__global__ void qsetup_kernel(const float* __restrict__ qw, float* __restrict__ A) {
    __shared__ float Ur[16][17];  // Ur[col][k] = Re U[k][col]
    __shared__ float Ui[16][17];
    __shared__ float sM[4 * 16 * 16];
    const int tid = threadIdx.x;

    if (tid < 16) {
        float sr[16], si[16];
        #pragma unroll
        for (int k = 0; k < 16; ++k) { sr[k] = (k == tid) ? 1.f : 0.f; si[k] = 0.f; }

        #pragma unroll
        for (int l = 0; l < NL; ++l) {
            #pragma unroll
            for (int w = 0; w < NQ; ++w) {
                float phi = qw[(l * NQ + w) * 3 + 0];
                float th  = qw[(l * NQ + w) * 3 + 1];
                float om  = qw[(l * NQ + w) * 3 + 2];
                float ct = cosf(0.5f * th), st = sinf(0.5f * th);
                float a = 0.5f * (phi + om), b = 0.5f * (phi - om);
                float sa, ca, sb, cb;
                sincosf(a, &sa, &ca);
                sincosf(b, &sb, &cb);
                float u00r =  ca * ct, u00i = -sa * ct;
                float u01r = -cb * st, u01i = -sb * st;
                float u10r =  cb * st, u10i = -sb * st;
                float u11r =  ca * ct, u11i =  sa * ct;
                const int wm = 1 << (3 - w);
                #pragma unroll
                for (int i = 0; i < 16; ++i) {
                    if (i & wm) continue;
                    int i1 = i | wm;
                    float a0r = sr[i],  a0i = si[i];
                    float a1r = sr[i1], a1i = si[i1];
                    sr[i]  = u00r * a0r - u00i * a0i + u01r * a1r - u01i * a1i;
                    si[i]  = u00r * a0i + u00i * a0r + u01r * a1i + u01i * a1r;
                    sr[i1] = u10r * a0r - u10i * a0i + u11r * a1r - u11i * a1i;
                    si[i1] = u10r * a0i + u10i * a0r + u11r * a1i + u11i * a1r;
                }
            }
            const int r = l % (NQ - 1) + 1;
            #pragma unroll
            for (int w = 0; w < NQ; ++w) {
                const int cm = 1 << (3 - w);
                const int tm = 1 << (3 - ((w + r) % NQ));
                #pragma unroll
                for (int i = 0; i < 16; ++i) {
                    if ((i & cm) && !(i & tm)) {
                        int i1 = i | tm;
                        float t;
                        t = sr[i]; sr[i] = sr[i1]; sr[i1] = t;
                        t = si[i]; si[i] = si[i1]; si[i1] = t;
                    }
                }
            }
        }
        #pragma unroll
        for (int k = 0; k < 16; ++k) { Ur[tid][k] = sr[k]; Ui[tid][k] = si[k]; }
    }
    __syncthreads();

    for (int t = tid; t < 4 * 16 * 16; t += blockDim.x) {
        int w = t >> 8, rem = t & 255, i = rem >> 4, j = rem & 15;
        float acc = 0.f;
        #pragma unroll
        for (int k = 0; k < 16; ++k) {
            float sgn = ((k >> (3 - w)) & 1) ? -1.f : 1.f;
            acc += sgn * (Ur[i][k] * Ur[j][k] + Ui[i][k] * Ui[j][k]);
        }
        sM[t] = acc;
    }
    __syncthreads();

    for (int t = tid; t < 4 * 81; t += blockDim.x) {
        int w = t / 81, j = t % 81;
        int j0 = j / 27, j1 = (j / 9) % 3, j2 = (j / 3) % 3, j3 = j % 3;
        int f =  ((j0 == 2) ? 8 : 0) | ((j1 == 2) ? 4 : 0)
               | ((j2 == 2) ? 2 : 0) | ((j3 == 2) ? 1 : 0);
        int zm = ((j0 == 1) ? 8 : 0) | ((j1 == 1) ? 4 : 0)
               | ((j2 == 1) ? 2 : 0) | ((j3 == 1) ? 1 : 0);
        float acc = 0.f;
        #pragma unroll
        for (int i = 0; i < 16; ++i) {
            float sgn = (__popc(i & zm) & 1) ? -1.f : 1.f;
            acc += sM[(w * 16 + (i ^ f)) * 16 + i] * sgn;
        }
        A[t] = acc * 0.0625f;
    }
}

// ---------------------------------------------------------------------------
// Main fused kernel (R4 skeleton): one thread per pixel.
//   - PLAIN 32-deep batched loads: x becomes L2/L3-resident across replays
//     (R8 evidence: FETCH ~ 0 in steady state with this policy)
//   - hardware __sinf/__cosf (error budget has 6x headroom)
//   - NT stores: stream 64MB of writes without polluting L2/L3
// ---------------------------------------------------------------------------
__global__ __launch_bounds__(256) void qmain_kernel(
    const float* __restrict__ x, const float* __restrict__ pre_w,
    const float* __restrict__ pre_b, const float* __restrict__ A,
    const float* __restrict__ post_w, const float* __restrict__ post_b,
    float* __restrict__ out)
{
    const int tid = threadIdx.x;
    const int p  = blockIdx.x * 256 + tid;   // pixel id
    const int n  = p >> 14;                  // / HWSZ
    const int hw = p & (HWSZ - 1);
    const float* xp = x + (size_t)n * CD * HWSZ + hw;

    float a0 = pre_b[0], a1 = pre_b[1], a2 = pre_b[2], a3 = pre_b[3];
    #pragma unroll
    for (int c0 = 0; c0 < CD; c0 += 32) {
        float xv[32];
        #pragma unroll
        for (int j = 0; j < 32; ++j)
            xv[j] = xp[(size_t)(c0 + j) * HWSZ];
        #pragma unroll
        for (int j = 0; j < 32; ++j) {
            const int c = c0 + j;
            a0 = fmaf(xv[j], pre_w[0 * CD + c], a0);
            a1 = fmaf(xv[j], pre_w[1 * CD + c], a1);
            a2 = fmaf(xv[j], pre_w[2 * CD + c], a2);
            a3 = fmaf(xv[j], pre_w[3 * CD + c], a3);
        }
    }

    const float PI = 3.14159265358979323846f;
    float cz0 = __cosf(PI * a0), sx0 = __sinf(PI * a0);
    float cz1 = __cosf(PI * a1), sx1 = __sinf(PI * a1);
    float cz2 = __cosf(PI * a2), sx2 = __sinf(PI * a2);
    float cz3 = __cosf(PI * a3), sx3 = __sinf(PI * a3);

    float g01[9], g23[9];
    {
        float t0[3] = { 1.f, cz0, sx0 }, t1[3] = { 1.f, cz1, sx1 };
        float t2[3] = { 1.f, cz2, sx2 }, t3[3] = { 1.f, cz3, sx3 };
        #pragma unroll
        for (int a = 0; a < 3; ++a)
            #pragma unroll
            for (int b = 0; b < 3; ++b) {
                g01[a * 3 + b] = t0[a] * t1[b];
                g23[a * 3 + b] = t2[a] * t3[b];
            }
    }

    float z0 = 0.f, z1 = 0.f, z2 = 0.f, z3 = 0.f;
    #pragma unroll
    for (int j01 = 0; j01 < 9; ++j01)
        #pragma unroll
        for (int j23 = 0; j23 < 9; ++j23) {
            float g = g01[j01] * g23[j23];
            int j = j01 * 9 + j23;
            z0 = fmaf(A[  0 + j], g, z0);
            z1 = fmaf(A[ 81 + j], g, z1);
            z2 = fmaf(A[162 + j], g, z2);
            z3 = fmaf(A[243 + j], g, z3);
        }

    float* op = out + (size_t)n * OUTC * HWSZ + hw;
    #pragma unroll 8
    for (int o = 0; o < OUTC; ++o) {
        float val = fmaf(z0, post_w[o * NQ + 0],
                    fmaf(z1, post_w[o * NQ + 1],
                    fmaf(z2, post_w[o * NQ + 2],
                    fmaf(z3, post_w[o * NQ + 3], post_b[o]))));
        __builtin_nontemporal_store(val, &op[(size_t)o * HWSZ]);
    }
}

extern "C" void kernel_launch(void* const* d_in, const int* in_sizes, int n_in,
                              void* d_out, int out_size, void* d_ws, size_t ws_size,
                              hipStream_t stream) {
    const float* x      = (const float*)d_in[0];
    const float* pre_w  = (const float*)d_in[1];
    const float* pre_b  = (const float*)d_in[2];
    const float* qw     = (const float*)d_in[3];
    const float* post_w = (const float*)d_in[4];
    const float* post_b = (const float*)d_in[5];
    float* out = (float*)d_out;
    float* A   = (float*)d_ws;   // 4*81 floats

    hipLaunchKernelGGL(qsetup_kernel, dim3(1), dim3(256), 0, stream, qw, A);

    const int B = in_sizes[0] / CD;   // N*H*W pixels
    hipLaunchKernelGGL(qmain_kernel, dim3(B / 256), dim3(256), 0, stream,
                       x, pre_w, pre_b, A, post_w, post_b, out);
}

// Round 11
// 42.032 us; speedup vs baseline: 2.1821x; 1.0764x over previous
//
#include <hip/hip_runtime.h>
#include <math.h>

#define NQ   4
#define NL   2
#define CD   128      // C
#define HWSZ 16384    // H*W
#define OUTC 128      // OUT

typedef float f4 __attribute__((ext_vector_type(4)));

// ---------------------------------------------------------------------------
// Setup kernel: build A[4][81] Pauli-string coefficients from circuit weights.
//   z_w(pixel) = sum_j A[w][j] * prod_i t_{i, j_i},  t_i = (1, cos(pi*xq_i), sin(pi*xq_i))
// ---------------------------------------------------------------------------
__global__ void qsetup_kernel(const float* __restrict__ qw, float* __restrict__ A) {
    __shared__ float Ur[16][17];  // Ur[col][k] = Re U[k][col]
    __shared__ float Ui[16][17];
    __shared__ float sM[4 * 16 * 16];
    const int tid = threadIdx.x;

    if (tid < 16) {
        float sr[16], si[16];
        #pragma unroll
        for (int k = 0; k < 16; ++k) { sr[k] = (k == tid) ? 1.f : 0.f; si[k] = 0.f; }

        #pragma unroll
        for (int l = 0; l < NL; ++l) {
            #pragma unroll
            for (int w = 0; w < NQ; ++w) {
                float phi = qw[(l * NQ + w) * 3 + 0];
                float th  = qw[(l * NQ + w) * 3 + 1];
                float om  = qw[(l * NQ + w) * 3 + 2];
                float ct = __cosf(0.5f * th), st = __sinf(0.5f * th);
                float a = 0.5f * (phi + om), b = 0.5f * (phi - om);
                float sa, ca, sb, cb;
                __sincosf(a, &sa, &ca);
                __sincosf(b, &sb, &cb);
                float u00r =  ca * ct, u00i = -sa * ct;
                float u01r = -cb * st, u01i = -sb * st;
                float u10r =  cb * st, u10i = -sb * st;
                float u11r =  ca * ct, u11i =  sa * ct;
                const int wm = 1 << (3 - w);
                #pragma unroll
                for (int i = 0; i < 16; ++i) {
                    if (i & wm) continue;
                    int i1 = i | wm;
                    float a0r = sr[i],  a0i = si[i];
                    float a1r = sr[i1], a1i = si[i1];
                    sr[i]  = u00r * a0r - u00i * a0i + u01r * a1r - u01i * a1i;
                    si[i]  = u00r * a0i + u00i * a0r + u01r * a1i + u01i * a1r;
                    sr[i1] = u10r * a0r - u10i * a0i + u11r * a1r - u11i * a1i;
                    si[i1] = u10r * a0i + u10i * a0r + u11r * a1i + u11i * a1r;
                }
            }
            const int r = l % (NQ - 1) + 1;
            #pragma unroll
            for (int w = 0; w < NQ; ++w) {
                const int cm = 1 << (3 - w);
                const int tm = 1 << (3 - ((w + r) % NQ));
                #pragma unroll
                for (int i = 0; i < 16; ++i) {
                    if ((i & cm) && !(i & tm)) {
                        int i1 = i | tm;
                        float t;
                        t = sr[i]; sr[i] = sr[i1]; sr[i1] = t;
                        t = si[i]; si[i] = si[i1]; si[i1] = t;
                    }
                }
            }
        }
        #pragma unroll
        for (int k = 0; k < 16; ++k) { Ur[tid][k] = sr[k]; Ui[tid][k] = si[k]; }
    }
    __syncthreads();

    for (int t = tid; t < 4 * 16 * 16; t += blockDim.x) {
        int w = t >> 8, rem = t & 255, i = rem >> 4, j = rem & 15;
        float acc = 0.f;
        #pragma unroll
        for (int k = 0; k < 16; ++k) {
            float sgn = ((k >> (3 - w)) & 1) ? -1.f : 1.f;
            acc += sgn * (Ur[i][k] * Ur[j][k] + Ui[i][k] * Ui[j][k]);
        }
        sM[t] = acc;
    }
    __syncthreads();

    for (int t = tid; t < 4 * 81; t += blockDim.x) {
        int w = t / 81, j = t % 81;
        int j0 = j / 27, j1 = (j / 9) % 3, j2 = (j / 3) % 3, j3 = j % 3;
        int f =  ((j0 == 2) ? 8 : 0) | ((j1 == 2) ? 4 : 0)
               | ((j2 == 2) ? 2 : 0) | ((j3 == 2) ? 1 : 0);
        int zm = ((j0 == 1) ? 8 : 0) | ((j1 == 1) ? 4 : 0)
               | ((j2 == 1) ? 2 : 0) | ((j3 == 1) ? 1 : 0);
        float acc = 0.f;
        #pragma unroll
        for (int i = 0; i < 16; ++i) {
            float sgn = (__popc(i & zm) & 1) ? -1.f : 1.f;
            acc += sM[(w * 16 + (i ^ f)) * 16 + i] * sgn;
        }
        A[t] = acc * 0.0625f;
    }
}

// ---------------------------------------------------------------------------
// Main fused kernel. Phase 1 (thread = pixel): 32-deep batched PLAIN scalar
// loads (x stays L3-resident across replays; R8 evidence FETCH~0), dot,
// __sinf circuit via Pauli coefficients, z -> LDS (4KB, [k][w][quad],
// 2-way bank alias = free). Phase 2 (thread = (quad, o-group)): each wave
// streams 32 contiguous 1KB NT f4-stores -- the write stream runs at the
// wide-instruction rate (~6.5 TB/s like fillBuffer) instead of the 256B/instr
// rate (~3.4 TB/s) that capped all previous rounds.
// ---------------------------------------------------------------------------
__global__ __launch_bounds__(256) void qmain_kernel(
    const float* __restrict__ x, const float* __restrict__ pre_w,
    const float* __restrict__ pre_b, const float* __restrict__ A,
    const float* __restrict__ post_w, const float* __restrict__ post_b,
    float* __restrict__ out)
{
    __shared__ float zL[4][4][64];   // [px&3][w][px>>2]

    const int tid    = threadIdx.x;
    const int blk    = blockIdx.x;
    const int n      = blk >> 6;                // 64 blocks per image
    const int hwbase = (blk & 63) * 256;
    const float* xp  = x + (size_t)n * CD * HWSZ + hwbase + tid;

    // ---- phase 1: dot + circuit for this thread's pixel ----
    float a0 = pre_b[0], a1 = pre_b[1], a2 = pre_b[2], a3 = pre_b[3];
    #pragma unroll
    for (int c0 = 0; c0 < CD; c0 += 32) {
        float xv[32];
        #pragma unroll
        for (int j = 0; j < 32; ++j)
            xv[j] = xp[(size_t)(c0 + j) * HWSZ];
        #pragma unroll
        for (int j = 0; j < 32; ++j) {
            const int c = c0 + j;
            a0 = fmaf(xv[j], pre_w[0 * CD + c], a0);
            a1 = fmaf(xv[j], pre_w[1 * CD + c], a1);
            a2 = fmaf(xv[j], pre_w[2 * CD + c], a2);
            a3 = fmaf(xv[j], pre_w[3 * CD + c], a3);
        }
    }

    const float PI = 3.14159265358979323846f;
    float cz0 = __cosf(PI * a0), sx0 = __sinf(PI * a0);
    float cz1 = __cosf(PI * a1), sx1 = __sinf(PI * a1);
    float cz2 = __cosf(PI * a2), sx2 = __sinf(PI * a2);
    float cz3 = __cosf(PI * a3), sx3 = __sinf(PI * a3);

    float g01[9], g23[9];
    {
        float t0[3] = { 1.f, cz0, sx0 }, t1[3] = { 1.f, cz1, sx1 };
        float t2[3] = { 1.f, cz2, sx2 }, t3[3] = { 1.f, cz3, sx3 };
        #pragma unroll
        for (int a = 0; a < 3; ++a)
            #pragma unroll
            for (int b = 0; b < 3; ++b) {
                g01[a * 3 + b] = t0[a] * t1[b];
                g23[a * 3 + b] = t2[a] * t3[b];
            }
    }

    float z0 = 0.f, z1 = 0.f, z2 = 0.f, z3 = 0.f;
    #pragma unroll
    for (int j01 = 0; j01 < 9; ++j01)
        #pragma unroll
        for (int j23 = 0; j23 < 9; ++j23) {
            float g = g01[j01] * g23[j23];
            int j = j01 * 9 + j23;
            z0 = fmaf(A[  0 + j], g, z0);
            z1 = fmaf(A[ 81 + j], g, z1);
            z2 = fmaf(A[162 + j], g, z2);
            z3 = fmaf(A[243 + j], g, z3);
        }

    zL[tid & 3][0][tid >> 2] = z0;
    zL[tid & 3][1][tid >> 2] = z1;
    zL[tid & 3][2][tid >> 2] = z2;
    zL[tid & 3][3][tid >> 2] = z3;
    __syncthreads();

    // ---- phase 2: wide coalesced write-out ----
    const int quad = tid & 63;      // pixel quad within the block's 256 px
    const int og   = tid >> 6;      // o-group: outputs [32*og, 32*og+32)

    float zq[4][4];                 // zq[k][w] = z_w of pixel quad*4+k
    #pragma unroll
    for (int k = 0; k < 4; ++k)
        #pragma unroll
        for (int w = 0; w < 4; ++w)
            zq[k][w] = zL[k][w][quad];

    float* op = out + (size_t)n * OUTC * HWSZ + (size_t)(og * 32) * HWSZ
                    + hwbase + quad * 4;
    #pragma unroll 8
    for (int i = 0; i < 32; ++i) {
        const int o = og * 32 + i;
        const f4 wv = *reinterpret_cast<const f4*>(&post_w[o * NQ]);
        const float bias = post_b[o];
        f4 v;
        #pragma unroll
        for (int k = 0; k < 4; ++k)
            v[k] = fmaf(zq[k][0], wv.x, fmaf(zq[k][1], wv.y,
                   fmaf(zq[k][2], wv.z, fmaf(zq[k][3], wv.w, bias))));
        __builtin_nontemporal_store(v, reinterpret_cast<f4*>(&op[(size_t)i * HWSZ]));
    }
}

extern "C" void kernel_launch(void* const* d_in, const int* in_sizes, int n_in,
                              void* d_out, int out_size, void* d_ws, size_t ws_size,
                              hipStream_t stream) {
    const float* x      = (const float*)d_in[0];
    const float* pre_w  = (const float*)d_in[1];
    const float* pre_b  = (const float*)d_in[2];
    const float* qw     = (const float*)d_in[3];
    const float* post_w = (const float*)d_in[4];
    const float* post_b = (const float*)d_in[5];
    float* out = (float*)d_out;
    float* A   = (float*)d_ws;   // 4*81 floats

    hipLaunchKernelGGL(qsetup_kernel, dim3(1), dim3(256), 0, stream, qw, A);

    const int B = in_sizes[0] / CD;   // N*H*W pixels
    hipLaunchKernelGGL(qmain_kernel, dim3(B / 256), dim3(256), 0, stream,
                       x, pre_w, pre_b, A, post_w, post_b, out);
}